// Round 1
// baseline (86.527 us; speedup 1.0000x reference)
//
#include <hip/hip_runtime.h>

#define HRr 30
#define WRr 40
#define MM 1200      // HRr*WRr
#define CC 128
#define NB 8
#define GS 8

constexpr int BM = 64, BN = 64, BK = 32;
constexpr int PT = (MM + BM - 1) / BM;   // 19 tiles per dim
constexpr int NPART = NB * PT * PT;      // 2888 partial sums

// ---------------- Kernel A: warped grid + reduced mask ----------------
__global__ __launch_bounds__(256) void prep_kernel(const float* __restrict__ mask,
                                                   const float* __restrict__ homo,
                                                   float2* __restrict__ wgrid,
                                                   float* __restrict__ out_rmask) {
    int id = blockIdx.x * 256 + threadIdx.x;
    if (id < MM) {
        int k = id / WRr, l = id % WRr;
        float x = (float)(l * GS + GS / 2);
        float y = (float)(k * GS + GS / 2);
        float h00 = homo[0], h01 = homo[1], h02 = homo[2];
        float h10 = homo[3], h11 = homo[4], h12 = homo[5];
        float h20 = homo[6], h21 = homo[7], h22 = homo[8];
        float nx = h00 * x + h01 * y + h02;
        float ny = h10 * x + h11 * y + h12;
        float dn = h20 * x + h21 * y + h22;
        wgrid[id] = make_float2(nx / dn, ny / dn);
    }
    if (id < NB * MM) {
        int n = id / MM;
        int rem = id % MM;
        int k = rem / WRr, l = rem % WRr;
        const float* mp = mask + (size_t)n * (240 * 320) + (size_t)(k * GS) * 320 + l * GS;
        float prod = 1.f;
        #pragma unroll
        for (int yy = 0; yy < GS; ++yy)
            #pragma unroll
            for (int xx = 0; xx < GS; ++xx)
                prod *= mp[yy * 320 + xx];
        out_rmask[id] = prod;
    }
}

// ---------------- Kernel B: tiled GEMM + fused epilogue ----------------
__global__ __launch_bounds__(256) void main_kernel(const float* __restrict__ des1,
                                                   const float* __restrict__ des2,
                                                   const float2* __restrict__ wgrid,
                                                   const float* __restrict__ rmask,
                                                   float* __restrict__ out_s,
                                                   float* __restrict__ out_dot,
                                                   float* __restrict__ partials) {
    __shared__ float smem[2 * BK * BM];          // As | Bs, reused as Ds in epilogue
    float* As = smem;                            // [BK][BM]
    float* Bs = smem + BK * BM;                  // [BK][BN]
    __shared__ float red[256];

    const int n  = blockIdx.z;
    const int p0 = blockIdx.y * BM;
    const int q0 = blockIdx.x * BN;
    const int t  = threadIdx.x;
    const int ty = t >> 4;       // 0..15  (p micro-tile)
    const int tx = t & 15;       // 0..15  (q micro-tile)

    const float* A = des1 + (size_t)n * CC * MM;
    const float* B = des2 + (size_t)n * CC * MM;

    float acc[4][4] = {};

    for (int k0 = 0; k0 < CC; k0 += BK) {
        // cooperative load: 2048 floats per operand, 512 float4 slots, 2 per thread
        #pragma unroll
        for (int it = 0; it < 2; ++it) {
            int slot = t + it * 256;
            int kk = slot >> 4;             // 0..31
            int pp = (slot & 15) << 2;      // 0..60
            int gp = p0 + pp;
            float4 va;
            if (gp + 3 < MM) {
                va = *reinterpret_cast<const float4*>(&A[(size_t)(k0 + kk) * MM + gp]);
            } else {
                float tmp[4];
                #pragma unroll
                for (int r = 0; r < 4; ++r) tmp[r] = (gp + r < MM) ? A[(size_t)(k0 + kk) * MM + gp + r] : 0.f;
                va = make_float4(tmp[0], tmp[1], tmp[2], tmp[3]);
            }
            *reinterpret_cast<float4*>(&As[kk * BM + pp]) = va;

            int gq = q0 + pp;
            float4 vb;
            if (gq + 3 < MM) {
                vb = *reinterpret_cast<const float4*>(&B[(size_t)(k0 + kk) * MM + gq]);
            } else {
                float tmp[4];
                #pragma unroll
                for (int r = 0; r < 4; ++r) tmp[r] = (gq + r < MM) ? B[(size_t)(k0 + kk) * MM + gq + r] : 0.f;
                vb = make_float4(tmp[0], tmp[1], tmp[2], tmp[3]);
            }
            *reinterpret_cast<float4*>(&Bs[kk * BN + pp]) = vb;
        }
        __syncthreads();

        #pragma unroll
        for (int kk = 0; kk < BK; ++kk) {
            float4 a4 = *reinterpret_cast<const float4*>(&As[kk * BM + ty * 4]);
            float4 b4 = *reinterpret_cast<const float4*>(&Bs[kk * BN + tx * 4]);
            float av[4] = {a4.x, a4.y, a4.z, a4.w};
            float bv[4] = {b4.x, b4.y, b4.z, b4.w};
            #pragma unroll
            for (int i2 = 0; i2 < 4; ++i2)
                #pragma unroll
                for (int j2 = 0; j2 < 4; ++j2)
                    acc[i2][j2] = fmaf(av[i2], bv[j2], acc[i2][j2]);
        }
        __syncthreads();
    }

    // stage the 64x64 dot tile through LDS so output stores are coalesced
    float* Ds = smem;   // 4096 floats, aliases As/Bs (synced above)
    #pragma unroll
    for (int i2 = 0; i2 < 4; ++i2)
        #pragma unroll
        for (int j2 = 0; j2 < 4; ++j2)
            Ds[(ty * 4 + i2) * BN + tx * 4 + j2] = acc[i2][j2];
    __syncthreads();

    float lsum = 0.f;
    #pragma unroll
    for (int r = 0; r < 16; ++r) {
        int idx = t + r * 256;               // 0..4095
        int row = idx >> 6;                  // /64
        int col = idx & 63;
        int p = p0 + row;
        int q = q0 + col;
        if (p < MM && q < MM) {
            float dot = Ds[idx];
            float gx = (float)((p % WRr) * GS + GS / 2);
            float gy = (float)((p / WRr) * GS + GS / 2);
            float2 w = wgrid[q];
            float dx = gx - w.x;
            float dy = gy - w.y;
            float dist = sqrtf(dx * dx + dy * dy);
            float s = (dist <= (float)GS - 0.5f) ? 1.f : 0.f;
            float pos = fmaxf(1.f - dot, 0.f);
            float neg = fmaxf(dot - 0.2f, 0.f);
            float le = 250.f * s * pos + (1.f - s) * neg;
            lsum += le * rmask[n * MM + q];
            size_t base = ((size_t)(n * MM + p)) * MM + q;
            out_dot[base] = dot;
            out_s[base] = s;
        }
    }

    // block reduction of the loss partial
    red[t] = lsum;
    __syncthreads();
    for (int off = 128; off > 0; off >>= 1) {
        if (t < off) red[t] += red[t + off];
        __syncthreads();
    }
    if (t == 0)
        partials[(size_t)blockIdx.z * (PT * PT) + blockIdx.y * PT + blockIdx.x] = red[0];
}

// ---------------- Kernel C: deterministic final reduction ----------------
__global__ __launch_bounds__(256) void final_kernel(const float* __restrict__ partials,
                                                    const float* __restrict__ rmask,
                                                    float* __restrict__ out_loss) {
    __shared__ float red[256];
    int t = threadIdx.x;

    float s1 = 0.f;
    for (int i = t; i < NPART; i += 256) s1 += partials[i];
    red[t] = s1;
    __syncthreads();
    for (int off = 128; off > 0; off >>= 1) {
        if (t < off) red[t] += red[t + off];
        __syncthreads();
    }
    float total = red[0];
    __syncthreads();

    float s2 = 0.f;
    for (int i = t; i < NB * MM; i += 256) s2 += rmask[i];
    red[t] = s2;
    __syncthreads();
    for (int off = 128; off > 0; off >>= 1) {
        if (t < off) red[t] += red[t + off];
        __syncthreads();
    }
    if (t == 0) out_loss[0] = total / ((float)MM * red[0]);
}

extern "C" void kernel_launch(void* const* d_in, const int* in_sizes, int n_in,
                              void* d_out, int out_size, void* d_ws, size_t ws_size,
                              hipStream_t stream) {
    const float* des1 = (const float*)d_in[0];
    const float* des2 = (const float*)d_in[1];
    const float* homo = (const float*)d_in[2];
    const float* mask = (const float*)d_in[3];

    float* out      = (float*)d_out;
    float* out_loss = out;                              // 1
    float* out_s    = out + 1;                          // 11,520,000
    float* out_dot  = out + 1 + (size_t)NB * MM * MM;   // 11,520,000
    float* out_rm   = out + 1 + 2 * (size_t)NB * MM * MM; // 9,600

    float*  ws       = (float*)d_ws;
    float2* wgrid    = (float2*)ws;        // 2400 floats
    float*  partials = ws + 2 * MM;        // NPART floats

    prep_kernel<<<(NB * MM + 255) / 256, 256, 0, stream>>>(mask, homo, wgrid, out_rm);

    dim3 grid(PT, PT, NB);
    main_kernel<<<grid, 256, 0, stream>>>(des1, des2, wgrid, out_rm, out_s, out_dot, partials);

    final_kernel<<<1, 256, 0, stream>>>(partials, out_rm, out_loss);
}

// Round 2
// 66.252 us; speedup vs baseline: 1.3060x; 1.3060x over previous
//
#include <hip/hip_runtime.h>
#include <hip/hip_bf16.h>

#define HRr 30
#define WRr 40
#define MM 1200      // HRr*WRr
#define CC 128
#define NB 8
#define GS 8

constexpr int BM = 64, BN = 64;
constexpr int PT = (MM + BM - 1) / BM;   // 19 tiles per dim
constexpr int NPART = NB * PT * PT;      // 2888 partial sums

typedef __attribute__((ext_vector_type(8))) short bf16x8;
typedef __attribute__((ext_vector_type(4))) float f32x4;

__device__ inline short f2bf(float f) {
    union { float f; unsigned u; } v; v.f = f;
    unsigned r = v.u + 0x7FFFu + ((v.u >> 16) & 1u);   // RNE
    return (short)(r >> 16);
}

// ---------------- Kernel A: warped grid + reduced mask ----------------
__global__ __launch_bounds__(256) void prep_kernel(const float* __restrict__ mask,
                                                   const float* __restrict__ homo,
                                                   float2* __restrict__ wgrid,
                                                   float* __restrict__ out_rmask) {
    int id = blockIdx.x * 256 + threadIdx.x;
    if (id < MM) {
        int k = id / WRr, l = id % WRr;
        float x = (float)(l * GS + GS / 2);
        float y = (float)(k * GS + GS / 2);
        float h00 = homo[0], h01 = homo[1], h02 = homo[2];
        float h10 = homo[3], h11 = homo[4], h12 = homo[5];
        float h20 = homo[6], h21 = homo[7], h22 = homo[8];
        float nx = h00 * x + h01 * y + h02;
        float ny = h10 * x + h11 * y + h12;
        float dn = h20 * x + h21 * y + h22;
        wgrid[id] = make_float2(nx / dn, ny / dn);
    }
    if (id < NB * MM) {
        int n = id / MM;
        int rem = id % MM;
        int k = rem / WRr, l = rem % WRr;
        const float* mp = mask + (size_t)n * (240 * 320) + (size_t)(k * GS) * 320 + l * GS;
        float prod = 1.f;
        #pragma unroll
        for (int yy = 0; yy < GS; ++yy)
            #pragma unroll
            for (int xx = 0; xx < GS; ++xx)
                prod *= mp[yy * 320 + xx];
        out_rmask[id] = prod;
    }
}

// ---------------- Kernel B: MFMA GEMM + fused epilogue ----------------
// LDS tiles stored as Tile[row][k] (bf16), halfword index = row*128 + (k ^ ((row&15)<<3)).
// Swizzle keeps each 8-halfword K-run contiguous (16B) and spreads rows across
// all 16 granules of the 256B row -> ds_read_b128 is ~2-way (free).
__global__ __launch_bounds__(256) void main_kernel(const float* __restrict__ des1,
                                                   const float* __restrict__ des2,
                                                   const float2* __restrict__ wgrid,
                                                   const float* __restrict__ rmask,
                                                   float* __restrict__ out_s,
                                                   float* __restrict__ out_dot,
                                                   float* __restrict__ partials) {
    __shared__ short As[64 * 128];
    __shared__ short Bs[64 * 128];
    __shared__ float red[256];

    const int n  = blockIdx.z;
    const int p0 = blockIdx.y * BM;
    const int q0 = blockIdx.x * BN;
    const int t  = threadIdx.x;

    const float* A = des1 + (size_t)n * CC * MM;
    const float* B = des2 + (size_t)n * CC * MM;

    // ---- stage both tiles: full K=128 in one shot, transpose + bf16 cvt ----
    const int j = t & 63;     // row within tile (p or q offset)
    const int g = t >> 6;     // wave id = k-run group
    const int p = p0 + j;
    const int q = q0 + j;

    #pragma unroll
    for (int it = 0; it < 4; ++it) {
        const int kb = (it * 4 + g) * 8;          // k base of this 8-run
        bf16x8 wa, wb;
        #pragma unroll
        for (int i = 0; i < 8; ++i) {
            float va = (p < MM) ? A[(size_t)(kb + i) * MM + p] : 0.f;  // coalesced per i
            float vb = (q < MM) ? B[(size_t)(kb + i) * MM + q] : 0.f;
            wa[i] = f2bf(va);
            wb[i] = f2bf(vb);
        }
        *reinterpret_cast<bf16x8*>(&As[j * 128 + (kb ^ ((j & 15) << 3))]) = wa;
        *reinterpret_cast<bf16x8*>(&Bs[j * 128 + (kb ^ ((j & 15) << 3))]) = wb;
    }
    __syncthreads();

    // ---- MFMA: 4 waves, each a 32x32 sub-tile = 2x2 fragments of 16x16 ----
    const int l  = t & 63;
    const int lr = l >> 4;        // lane group 0..3
    const int lc = l & 15;
    const int w  = t >> 6;
    const int wrow = (w >> 1) * 32;
    const int wcol = (w & 1) * 32;

    f32x4 acc[2][2] = {};
    #pragma unroll
    for (int ks = 0; ks < 4; ++ks) {
        const int kb = ks * 32 + lr * 8;
        bf16x8 af[2], bfr[2];
        #pragma unroll
        for (int f = 0; f < 2; ++f) {
            const int m  = wrow + f * 16 + lc;
            const int nn = wcol + f * 16 + lc;
            af[f]  = *reinterpret_cast<const bf16x8*>(&As[m  * 128 + (kb ^ ((m  & 15) << 3))]);
            bfr[f] = *reinterpret_cast<const bf16x8*>(&Bs[nn * 128 + (kb ^ ((nn & 15) << 3))]);
        }
        #pragma unroll
        for (int fi = 0; fi < 2; ++fi)
            #pragma unroll
            for (int fj = 0; fj < 2; ++fj)
                acc[fi][fj] = __builtin_amdgcn_mfma_f32_16x16x32_bf16(af[fi], bfr[fj], acc[fi][fj], 0, 0, 0);
    }

    // ---- epilogue: s, dot stores + masked loss partial (f32, same math as R1) ----
    float lsum = 0.f;
    #pragma unroll
    for (int fi = 0; fi < 2; ++fi) {
        #pragma unroll
        for (int r = 0; r < 4; ++r) {
            const int pp = p0 + wrow + fi * 16 + lr * 4 + r;   // D row
            if (pp >= MM) continue;
            const float gx = (float)((pp % WRr) * GS + GS / 2);
            const float gy = (float)((pp / WRr) * GS + GS / 2);
            const size_t rowbase = ((size_t)(n * MM + pp)) * MM;
            #pragma unroll
            for (int fj = 0; fj < 2; ++fj) {
                const int qq = q0 + wcol + fj * 16 + lc;       // D col
                if (qq >= MM) continue;
                const float dot = acc[fi][fj][r];
                const float2 wg = wgrid[qq];
                const float dx = gx - wg.x;
                const float dy = gy - wg.y;
                const float dist = sqrtf(dx * dx + dy * dy);
                const float s = (dist <= (float)GS - 0.5f) ? 1.f : 0.f;
                const float pos = fmaxf(1.f - dot, 0.f);
                const float neg = fmaxf(dot - 0.2f, 0.f);
                const float le = 250.f * s * pos + (1.f - s) * neg;
                lsum += le * rmask[n * MM + qq];
                out_dot[rowbase + qq] = dot;
                out_s[rowbase + qq] = s;
            }
        }
    }

    // ---- block reduction of loss partial ----
    red[t] = lsum;
    __syncthreads();
    for (int off = 128; off > 0; off >>= 1) {
        if (t < off) red[t] += red[t + off];
        __syncthreads();
    }
    if (t == 0)
        partials[(size_t)blockIdx.z * (PT * PT) + blockIdx.y * PT + blockIdx.x] = red[0];
}

// ---------------- Kernel C: deterministic final reduction ----------------
__global__ __launch_bounds__(256) void final_kernel(const float* __restrict__ partials,
                                                    const float* __restrict__ rmask,
                                                    float* __restrict__ out_loss) {
    __shared__ float red[256];
    int t = threadIdx.x;

    float s1 = 0.f;
    for (int i = t; i < NPART; i += 256) s1 += partials[i];
    red[t] = s1;
    __syncthreads();
    for (int off = 128; off > 0; off >>= 1) {
        if (t < off) red[t] += red[t + off];
        __syncthreads();
    }
    float total = red[0];
    __syncthreads();

    float s2 = 0.f;
    for (int i = t; i < NB * MM; i += 256) s2 += rmask[i];
    red[t] = s2;
    __syncthreads();
    for (int off = 128; off > 0; off >>= 1) {
        if (t < off) red[t] += red[t + off];
        __syncthreads();
    }
    if (t == 0) out_loss[0] = total / ((float)MM * red[0]);
}

extern "C" void kernel_launch(void* const* d_in, const int* in_sizes, int n_in,
                              void* d_out, int out_size, void* d_ws, size_t ws_size,
                              hipStream_t stream) {
    const float* des1 = (const float*)d_in[0];
    const float* des2 = (const float*)d_in[1];
    const float* homo = (const float*)d_in[2];
    const float* mask = (const float*)d_in[3];

    float* out      = (float*)d_out;
    float* out_loss = out;                                // 1
    float* out_s    = out + 1;                            // 11,520,000
    float* out_dot  = out + 1 + (size_t)NB * MM * MM;     // 11,520,000
    float* out_rm   = out + 1 + 2 * (size_t)NB * MM * MM; // 9,600

    float*  ws       = (float*)d_ws;
    float2* wgrid    = (float2*)ws;        // 2400 floats
    float*  partials = ws + 2 * MM;        // NPART floats

    prep_kernel<<<(NB * MM + 255) / 256, 256, 0, stream>>>(mask, homo, wgrid, out_rm);

    dim3 grid(PT, PT, NB);
    main_kernel<<<grid, 256, 0, stream>>>(des1, des2, wgrid, out_rm, out_s, out_dot, partials);

    final_kernel<<<1, 256, 0, stream>>>(partials, out_rm, out_loss);
}

// Round 3
// 61.901 us; speedup vs baseline: 1.3978x; 1.0703x over previous
//
#include <hip/hip_runtime.h>
#include <hip/hip_bf16.h>

#define HRr 30
#define WRr 40
#define MM 1200      // HRr*WRr
#define CC 128
#define NB 8
#define GS 8

constexpr int BM = 64, BN = 64;
constexpr int PT = (MM + BM - 1) / BM;   // 19 tiles per dim
constexpr int NPART = NB * PT * PT;      // 2888 partial sums
constexpr int TILE_SH = 16 * 64 * 8;     // shorts per (n,tile) fragment block = 8192

typedef __attribute__((ext_vector_type(8))) short bf16x8;
typedef __attribute__((ext_vector_type(4))) float f32x4;

__device__ inline short f2bf(float f) {
    union { float f; unsigned u; } v; v.f = f;
    unsigned r = v.u + 0x7FFFu + ((v.u >> 16) & 1u);   // RNE
    return (short)(r >> 16);
}

// ---------------- Kernel A: warped grid + reduced mask ----------------
__global__ __launch_bounds__(256) void prep_kernel(const float* __restrict__ mask,
                                                   const float* __restrict__ homo,
                                                   float2* __restrict__ wgrid,
                                                   float* __restrict__ out_rmask) {
    int id = blockIdx.x * 256 + threadIdx.x;
    if (id < MM) {
        int k = id / WRr, l = id % WRr;
        float x = (float)(l * GS + GS / 2);
        float y = (float)(k * GS + GS / 2);
        float h00 = homo[0], h01 = homo[1], h02 = homo[2];
        float h10 = homo[3], h11 = homo[4], h12 = homo[5];
        float h20 = homo[6], h21 = homo[7], h22 = homo[8];
        float nx = h00 * x + h01 * y + h02;
        float ny = h10 * x + h11 * y + h12;
        float dn = h20 * x + h21 * y + h22;
        wgrid[id] = make_float2(nx / dn, ny / dn);
    }
    if (id < NB * MM) {
        int n = id / MM;
        int rem = id % MM;
        int k = rem / WRr, l = rem % WRr;
        const float* mp = mask + (size_t)n * (240 * 320) + (size_t)(k * GS) * 320 + l * GS;
        float prod = 1.f;
        #pragma unroll
        for (int yy = 0; yy < GS; ++yy)
            #pragma unroll
            for (int xx = 0; xx < GS; ++xx)
                prod *= mp[yy * 320 + xx];
        out_rmask[id] = prod;
    }
}

// ------- Kernel A2: f32 -> bf16 transpose into MFMA fragment order -------
// ws layout per (n, tile): [ks 0..3][rb 0..3][lane 0..63][8 halfwords]
// lane l = lr*16+lc holds (row = rb*16+lc, k = ks*32+lr*8 .. +7).
// Main-kernel fragment loads become 1KB fully-coalesced dwordx4 per wave.
__global__ __launch_bounds__(256) void convert_kernel(const float* __restrict__ des1,
                                                      const float* __restrict__ des2,
                                                      short* __restrict__ wsA,
                                                      short* __restrict__ wsB) {
    const int ptile = blockIdx.x;      // 0..18
    const int n     = blockIdx.z;      // 0..7
    const int t = threadIdx.x;
    const int j = t & 63;              // row within tile
    const int g = t >> 6;              // wave id = k-run group
    const int p = ptile * BM + j;

    const float* A = des1 + (size_t)n * CC * MM;
    const float* B = des2 + (size_t)n * CC * MM;
    short* outA = wsA + (size_t)(n * PT + ptile) * TILE_SH;
    short* outB = wsB + (size_t)(n * PT + ptile) * TILE_SH;

    const int rb = j >> 4, lc = j & 15;
    #pragma unroll
    for (int it = 0; it < 4; ++it) {
        const int kr = it * 4 + g;          // k-run index 0..15
        const int kb = kr * 8;
        bf16x8 wa, wb;
        #pragma unroll
        for (int i = 0; i < 8; ++i) {
            float va = (p < MM) ? A[(size_t)(kb + i) * MM + p] : 0.f;  // coalesced per i
            float vb = (p < MM) ? B[(size_t)(kb + i) * MM + p] : 0.f;
            wa[i] = f2bf(va);
            wb[i] = f2bf(vb);
        }
        const int ks = kr >> 2, lr = kr & 3;
        const size_t off = (size_t)(((ks * 4 + rb) * 64) + lr * 16 + lc) * 8;
        *reinterpret_cast<bf16x8*>(&outA[off]) = wa;
        *reinterpret_cast<bf16x8*>(&outB[off]) = wb;
    }
}

// ---------------- Kernel B: MFMA GEMM (no LDS staging) + fused epilogue ----------------
__global__ __launch_bounds__(256) void main_kernel(const short* __restrict__ wsA,
                                                   const short* __restrict__ wsB,
                                                   const float2* __restrict__ wgrid,
                                                   const float* __restrict__ rmask,
                                                   float* __restrict__ out_s,
                                                   float* __restrict__ out_dot,
                                                   float* __restrict__ partials) {
    __shared__ float red[256];

    const int n  = blockIdx.z;
    const int p0 = blockIdx.y * BM;
    const int q0 = blockIdx.x * BN;
    const int t  = threadIdx.x;
    const int l  = t & 63;
    const int lr = l >> 4;
    const int lc = l & 15;
    const int w  = t >> 6;
    const int wrow = (w >> 1) * 32;
    const int wcol = (w & 1) * 32;

    const short* Abase = wsA + (size_t)(n * PT + blockIdx.y) * TILE_SH;
    const short* Bbase = wsB + (size_t)(n * PT + blockIdx.x) * TILE_SH;

    f32x4 acc[2][2] = {};
    #pragma unroll
    for (int ks = 0; ks < 4; ++ks) {
        bf16x8 af[2], bfr[2];
        #pragma unroll
        for (int f = 0; f < 2; ++f) {
            const int rbA = (w >> 1) * 2 + f;
            const int rbB = (w & 1) * 2 + f;
            af[f]  = *reinterpret_cast<const bf16x8*>(&Abase[(size_t)(((ks * 4 + rbA) * 64) + l) * 8]);
            bfr[f] = *reinterpret_cast<const bf16x8*>(&Bbase[(size_t)(((ks * 4 + rbB) * 64) + l) * 8]);
        }
        #pragma unroll
        for (int fi = 0; fi < 2; ++fi)
            #pragma unroll
            for (int fj = 0; fj < 2; ++fj)
                acc[fi][fj] = __builtin_amdgcn_mfma_f32_16x16x32_bf16(af[fi], bfr[fj], acc[fi][fj], 0, 0, 0);
    }

    // ---- epilogue: s, dot stores + masked loss partial (identical math to R2) ----
    float lsum = 0.f;
    #pragma unroll
    for (int fi = 0; fi < 2; ++fi) {
        #pragma unroll
        for (int r = 0; r < 4; ++r) {
            const int pp = p0 + wrow + fi * 16 + lr * 4 + r;   // D row
            if (pp >= MM) continue;
            const float gx = (float)((pp % WRr) * GS + GS / 2);
            const float gy = (float)((pp / WRr) * GS + GS / 2);
            const size_t rowbase = ((size_t)(n * MM + pp)) * MM;
            #pragma unroll
            for (int fj = 0; fj < 2; ++fj) {
                const int qq = q0 + wcol + fj * 16 + lc;       // D col
                if (qq >= MM) continue;
                const float dot = acc[fi][fj][r];
                const float2 wg = wgrid[qq];
                const float dx = gx - wg.x;
                const float dy = gy - wg.y;
                const float dist = sqrtf(dx * dx + dy * dy);
                const float s = (dist <= (float)GS - 0.5f) ? 1.f : 0.f;
                const float pos = fmaxf(1.f - dot, 0.f);
                const float neg = fmaxf(dot - 0.2f, 0.f);
                const float le = 250.f * s * pos + (1.f - s) * neg;
                lsum += le * rmask[n * MM + qq];
                out_dot[rowbase + qq] = dot;
                out_s[rowbase + qq] = s;
            }
        }
    }

    // ---- block reduction of loss partial ----
    red[t] = lsum;
    __syncthreads();
    for (int off = 128; off > 0; off >>= 1) {
        if (t < off) red[t] += red[t + off];
        __syncthreads();
    }
    if (t == 0)
        partials[(size_t)blockIdx.z * (PT * PT) + blockIdx.y * PT + blockIdx.x] = red[0];
}

// ---------------- Kernel C: deterministic final reduction ----------------
__global__ __launch_bounds__(256) void final_kernel(const float* __restrict__ partials,
                                                    const float* __restrict__ rmask,
                                                    float* __restrict__ out_loss) {
    __shared__ float red[256];
    int t = threadIdx.x;

    float s1 = 0.f;
    for (int i = t; i < NPART; i += 256) s1 += partials[i];
    red[t] = s1;
    __syncthreads();
    for (int off = 128; off > 0; off >>= 1) {
        if (t < off) red[t] += red[t + off];
        __syncthreads();
    }
    float total = red[0];
    __syncthreads();

    float s2 = 0.f;
    for (int i = t; i < NB * MM; i += 256) s2 += rmask[i];
    red[t] = s2;
    __syncthreads();
    for (int off = 128; off > 0; off >>= 1) {
        if (t < off) red[t] += red[t + off];
        __syncthreads();
    }
    if (t == 0) out_loss[0] = total / ((float)MM * red[0]);
}

extern "C" void kernel_launch(void* const* d_in, const int* in_sizes, int n_in,
                              void* d_out, int out_size, void* d_ws, size_t ws_size,
                              hipStream_t stream) {
    const float* des1 = (const float*)d_in[0];
    const float* des2 = (const float*)d_in[1];
    const float* homo = (const float*)d_in[2];
    const float* mask = (const float*)d_in[3];

    float* out      = (float*)d_out;
    float* out_loss = out;                                // 1
    float* out_s    = out + 1;                            // 11,520,000
    float* out_dot  = out + 1 + (size_t)NB * MM * MM;     // 11,520,000
    float* out_rm   = out + 1 + 2 * (size_t)NB * MM * MM; // 9,600

    // workspace layout (byte offsets)
    char* wsb = (char*)d_ws;
    float2* wgrid    = (float2*)(wsb);                    // 9,600 B
    float*  partials = (float*)(wsb + 16384);             // 11,552 B
    short*  wsA      = (short*)(wsb + 32768);             // 2,490,368 B
    short*  wsB      = (short*)(wsb + 32768 + (size_t)NB * PT * TILE_SH * 2);

    prep_kernel<<<(NB * MM + 255) / 256, 256, 0, stream>>>(mask, homo, wgrid, out_rm);

    dim3 cgrid(PT, 1, NB);
    convert_kernel<<<cgrid, 256, 0, stream>>>(des1, des2, wsA, wsB);

    dim3 grid(PT, PT, NB);
    main_kernel<<<grid, 256, 0, stream>>>(wsA, wsB, wgrid, out_rm, out_s, out_dot, partials);

    final_kernel<<<1, 256, 0, stream>>>(partials, out_rm, out_loss);
}

// Round 4
// 48.135 us; speedup vs baseline: 1.7976x; 1.2860x over previous
//
#include <hip/hip_runtime.h>
#include <hip/hip_bf16.h>

#define HRr 30
#define WRr 40
#define MM 1200      // HRr*WRr
#define CC 128
#define NB 8
#define GS 8

constexpr int BM = 64, BN = 64;
constexpr int PT = (MM + BM - 1) / BM;   // 19 tiles per dim
constexpr int NPART = NB * PT * PT;      // 2888 partial sums
constexpr int TILE_SH = 16 * 64 * 8;     // shorts per (n,tile) fragment block = 8192

typedef __attribute__((ext_vector_type(8))) short bf16x8;
typedef __attribute__((ext_vector_type(4))) float f32x4;

__device__ inline short f2bf(float f) {
    union { float f; unsigned u; } v; v.f = f;
    unsigned r = v.u + 0x7FFFu + ((v.u >> 16) & 1u);   // RNE
    return (short)(r >> 16);
}

// ------- Kernel A: fused {warped grid, reduced mask, f32->bf16 fragment convert} -------
// Convert ws layout per (n, tile): [ks 0..3][rb 0..3][lane 0..63][8 halfwords]
// lane l = lr*16+lc holds (row = rb*16+lc, k = ks*32+lr*8 .. +7).
__global__ __launch_bounds__(256) void convert_prep_kernel(const float* __restrict__ des1,
                                                           const float* __restrict__ des2,
                                                           const float* __restrict__ homo,
                                                           const float* __restrict__ mask,
                                                           short* __restrict__ wsA,
                                                           short* __restrict__ wsB,
                                                           float2* __restrict__ wgrid,
                                                           float* __restrict__ out_rmask,
                                                           float* __restrict__ ws_rmask) {
    const int t     = threadIdx.x;
    const int ptile = blockIdx.x;      // 0..18
    const int n     = blockIdx.z;      // 0..7

    // ---- prep part (first 9600 threads of the 38912-thread grid) ----
    const int gid = (blockIdx.z * gridDim.x + blockIdx.x) * 256 + t;
    if (gid < MM) {
        int k = gid / WRr, l = gid % WRr;
        float x = (float)(l * GS + GS / 2);
        float y = (float)(k * GS + GS / 2);
        float nx = homo[0] * x + homo[1] * y + homo[2];
        float ny = homo[3] * x + homo[4] * y + homo[5];
        float dn = homo[6] * x + homo[7] * y + homo[8];
        wgrid[gid] = make_float2(nx / dn, ny / dn);
    }
    if (gid < NB * MM) {
        int nn = gid / MM;
        int rem = gid % MM;
        int k = rem / WRr, l = rem % WRr;
        const float* mp = mask + (size_t)nn * (240 * 320) + (size_t)(k * GS) * 320 + l * GS;
        float prod = 1.f;
        #pragma unroll
        for (int yy = 0; yy < GS; ++yy) {
            float4 a = *reinterpret_cast<const float4*>(&mp[yy * 320]);
            float4 b = *reinterpret_cast<const float4*>(&mp[yy * 320 + 4]);
            prod *= a.x * a.y * a.z * a.w * b.x * b.y * b.z * b.w;
        }
        out_rmask[gid] = prod;
        ws_rmask[gid]  = prod;
    }

    // ---- convert part ----
    const int j = t & 63;              // row within tile
    const int g = t >> 6;              // wave id = k-run group
    const int p = ptile * BM + j;

    const float* A = des1 + (size_t)n * CC * MM;
    const float* B = des2 + (size_t)n * CC * MM;
    short* outA = wsA + (size_t)(n * PT + ptile) * TILE_SH;
    short* outB = wsB + (size_t)(n * PT + ptile) * TILE_SH;

    const int rb = j >> 4, lc = j & 15;
    #pragma unroll
    for (int it = 0; it < 4; ++it) {
        const int kr = it * 4 + g;          // k-run index 0..15
        const int kb = kr * 8;
        bf16x8 wa, wb;
        #pragma unroll
        for (int i = 0; i < 8; ++i) {
            float va = (p < MM) ? A[(size_t)(kb + i) * MM + p] : 0.f;  // coalesced per i
            float vb = (p < MM) ? B[(size_t)(kb + i) * MM + p] : 0.f;
            wa[i] = f2bf(va);
            wb[i] = f2bf(vb);
        }
        const int ks = kr >> 2, lr = kr & 3;
        const size_t off = (size_t)(((ks * 4 + rb) * 64) + lr * 16 + lc) * 8;
        *reinterpret_cast<bf16x8*>(&outA[off]) = wa;
        *reinterpret_cast<bf16x8*>(&outB[off]) = wb;
    }
}

// ---------------- Kernel B: MFMA GEMM + LDS-staged linear epilogue ----------------
__global__ __launch_bounds__(256) void main_kernel(const short* __restrict__ wsA,
                                                   const short* __restrict__ wsB,
                                                   const float2* __restrict__ wgrid,
                                                   const float* __restrict__ rmask,
                                                   float* __restrict__ out_s,
                                                   float* __restrict__ out_dot,
                                                   float* __restrict__ partials) {
    __shared__ float Ds[64 * 68];       // dot tile, stride 68 (2-way banks = free)
    __shared__ float red[4];

    const int n  = blockIdx.z;
    const int p0 = blockIdx.y * BM;
    const int q0 = blockIdx.x * BN;
    const int t  = threadIdx.x;
    const int l  = t & 63;
    const int lr = l >> 4;
    const int lc = l & 15;
    const int w  = t >> 6;
    const int wrow = (w >> 1) * 32;
    const int wcol = (w & 1) * 32;

    const short* Abase = wsA + (size_t)(n * PT + blockIdx.y) * TILE_SH;
    const short* Bbase = wsB + (size_t)(n * PT + blockIdx.x) * TILE_SH;

    f32x4 acc[2][2] = {};
    #pragma unroll
    for (int ks = 0; ks < 4; ++ks) {
        bf16x8 af[2], bfr[2];
        #pragma unroll
        for (int f = 0; f < 2; ++f) {
            const int rbA = (w >> 1) * 2 + f;
            const int rbB = (w & 1) * 2 + f;
            af[f]  = *reinterpret_cast<const bf16x8*>(&Abase[(size_t)(((ks * 4 + rbA) * 64) + l) * 8]);
            bfr[f] = *reinterpret_cast<const bf16x8*>(&Bbase[(size_t)(((ks * 4 + rbB) * 64) + l) * 8]);
        }
        #pragma unroll
        for (int fi = 0; fi < 2; ++fi)
            #pragma unroll
            for (int fj = 0; fj < 2; ++fj)
                acc[fi][fj] = __builtin_amdgcn_mfma_f32_16x16x32_bf16(af[fi], bfr[fj], acc[fi][fj], 0, 0, 0);
    }

    // ---- stage dot tile into LDS (D row = lr*4+rr, col = lc within fragment) ----
    #pragma unroll
    for (int fi = 0; fi < 2; ++fi)
        #pragma unroll
        for (int fj = 0; fj < 2; ++fj)
            #pragma unroll
            for (int rr = 0; rr < 4; ++rr)
                Ds[(wrow + fi * 16 + lr * 4 + rr) * 68 + wcol + fj * 16 + lc] = acc[fi][fj][rr];
    __syncthreads();

    // ---- linear readout: each wave instruction writes 256B contiguous ----
    float lsum = 0.f;
    #pragma unroll
    for (int r = 0; r < 16; ++r) {
        const int idx = r * 256 + t;
        const int row = idx >> 6;            // uniform within a wave
        const int col = idx & 63;
        const int pp = p0 + row;
        const int qq = q0 + col;
        if (pp < MM) {
            const float gx = (float)((pp % WRr) * GS + GS / 2);
            const float gy = (float)((pp / WRr) * GS + GS / 2);
            const float dot = Ds[row * 68 + col];
            if (qq < MM) {
                const float2 wg = wgrid[qq];
                const float dx = gx - wg.x;
                const float dy = gy - wg.y;
                const float dist = sqrtf(dx * dx + dy * dy);
                const float s = (dist <= (float)GS - 0.5f) ? 1.f : 0.f;
                const float pos = fmaxf(1.f - dot, 0.f);
                const float neg = fmaxf(dot - 0.2f, 0.f);
                const float le = 250.f * s * pos + (1.f - s) * neg;
                lsum += le * rmask[n * MM + qq];
                const size_t gidx = ((size_t)(n * MM + pp)) * MM + qq;
                out_dot[gidx] = dot;
                out_s[gidx] = s;
            }
        }
    }

    // ---- wave shuffle reduce, then 4-entry LDS combine ----
    #pragma unroll
    for (int off = 32; off > 0; off >>= 1)
        lsum += __shfl_xor(lsum, off, 64);
    if (l == 0) red[w] = lsum;
    __syncthreads();
    if (t == 0)
        partials[(size_t)blockIdx.z * (PT * PT) + blockIdx.y * PT + blockIdx.x] =
            (red[0] + red[1]) + (red[2] + red[3]);
}

// ---------------- Kernel C: deterministic final reduction ----------------
__global__ __launch_bounds__(1024) void final_kernel(const float* __restrict__ partials,
                                                     const float* __restrict__ rmask,
                                                     float* __restrict__ out_loss) {
    __shared__ float red[1024];
    const int t = threadIdx.x;

    float s1 = 0.f;
    for (int i = t; i < NPART; i += 1024) s1 += partials[i];
    red[t] = s1;
    __syncthreads();
    for (int off = 512; off > 0; off >>= 1) {
        if (t < off) red[t] += red[t + off];
        __syncthreads();
    }
    float total = red[0];
    __syncthreads();

    float s2 = 0.f;
    for (int i = t; i < NB * MM; i += 1024) s2 += rmask[i];
    red[t] = s2;
    __syncthreads();
    for (int off = 512; off > 0; off >>= 1) {
        if (t < off) red[t] += red[t + off];
        __syncthreads();
    }
    if (t == 0) out_loss[0] = total / ((float)MM * red[0]);
}

extern "C" void kernel_launch(void* const* d_in, const int* in_sizes, int n_in,
                              void* d_out, int out_size, void* d_ws, size_t ws_size,
                              hipStream_t stream) {
    const float* des1 = (const float*)d_in[0];
    const float* des2 = (const float*)d_in[1];
    const float* homo = (const float*)d_in[2];
    const float* mask = (const float*)d_in[3];

    float* out      = (float*)d_out;
    float* out_loss = out;                                // 1
    float* out_s    = out + 1;                            // 11,520,000
    float* out_dot  = out + 1 + (size_t)NB * MM * MM;     // 11,520,000
    float* out_rm   = out + 1 + 2 * (size_t)NB * MM * MM; // 9,600

    // workspace layout (byte offsets, all 16B-aligned)
    char* wsb = (char*)d_ws;
    float2* wgrid    = (float2*)(wsb);                    //   9,600 B
    float*  partials = (float*)(wsb + 16384);             //  11,552 B
    float*  ws_rm    = (float*)(wsb + 32768);             //  38,400 B
    short*  wsA      = (short*)(wsb + 131072);            // 2,490,368 B
    short*  wsB      = wsA + (size_t)NB * PT * TILE_SH;   // 2,490,368 B

    dim3 cgrid(PT, 1, NB);
    convert_prep_kernel<<<cgrid, 256, 0, stream>>>(des1, des2, homo, mask,
                                                   wsA, wsB, wgrid, out_rm, ws_rm);

    dim3 grid(PT, PT, NB);
    main_kernel<<<grid, 256, 0, stream>>>(wsA, wsB, wgrid, ws_rm, out_s, out_dot, partials);

    final_kernel<<<1, 1024, 0, stream>>>(partials, ws_rm, out_loss);
}